// Round 4
// baseline (619.774 us; speedup 1.0000x reference)
//
#include <hip/hip_runtime.h>
#include <hip/hip_bf16.h>
#include <cstdint>
#include <cstddef>

// ---------------- problem constants ----------------
#define N_TOK   16384
#define DIM     1024
#define NE      8
#define CAP     2560        // int(1.25 * 16384 / 8)
#define NCHUNK  256         // 16384 / 64
#define NSLOT   (NE * CAP)  // 20480

// ---------------- sizes -----------------
#define APL_BYTES  ((size_t)NSLOT * DIM * 2)      // one bf16 plane of A/H: 41,943,040
#define WPL_BYTES  ((size_t)NE * DIM * DIM * 2)   // one bf16 plane of W:   16,777,216
#define H_BYTES    ((size_t)NSLOT * DIM * 4)      // fp32 h (fallback path)
#define TOK_BYTES  ((size_t)NSLOT * 4)
#define GATE_BYTES ((size_t)NSLOT * 4)
#define TIDX_BYTES ((size_t)N_TOK * 2 * 4)
#define TGT_BYTES  ((size_t)N_TOK * 2 * 4)
#define TSLOT_BYTES ((size_t)N_TOK * 2 * 4)
#define CC_BYTES   ((size_t)NE * NCHUNK * 4)
#define CO_BYTES   ((size_t)NE * NCHUNK * 4)
#define SMALL_BYTES (TOK_BYTES + GATE_BYTES + TIDX_BYTES + TGT_BYTES + TSLOT_BYTES + CC_BYTES + CO_BYTES)

typedef __attribute__((ext_vector_type(8))) short short8;
typedef __attribute__((ext_vector_type(4))) short short4v;
typedef __attribute__((ext_vector_type(4))) float floatx4;

// bf16 helpers (RN-even), bit-pattern in short
__device__ __forceinline__ short f2bf(float f) {
    union { float f; unsigned u; } c; c.f = f;
    unsigned r = (c.u + 0x7fffu + ((c.u >> 16) & 1u)) >> 16;
    return (short)r;
}
__device__ __forceinline__ float bf2f(short s) {
    union { unsigned u; float f; } c; c.u = ((unsigned)(unsigned short)s) << 16;
    return c.f;
}

__device__ __forceinline__ void gload_lds16(const void* g, void* l) {
    typedef const __attribute__((address_space(1))) unsigned int* gp_t;
    typedef __attribute__((address_space(3))) unsigned int* lp_t;
    __builtin_amdgcn_global_load_lds((gp_t)g, (lp_t)l, 16, 0, 0);
}

// ---------------------------------------------------
// Router: one wave per token. logits = x @ Wr^T + br, top-2, softmax gates.
__global__ __launch_bounds__(256) void router_kernel(
    const float* __restrict__ x, const float* __restrict__ Wr,
    const float* __restrict__ br, int* __restrict__ tokIdx,
    float* __restrict__ tokGate)
{
    int wave = threadIdx.x >> 6;
    int lane = threadIdx.x & 63;
    int t = blockIdx.x * 4 + wave;

    float acc[NE];
#pragma unroll
    for (int e = 0; e < NE; ++e) acc[e] = 0.f;

    const float4* xr = (const float4*)(x + (size_t)t * DIM);
#pragma unroll
    for (int j = 0; j < 4; ++j) {
        float4 xv = xr[j * 64 + lane];
#pragma unroll
        for (int e = 0; e < NE; ++e) {
            float4 wv = ((const float4*)(Wr + e * DIM))[j * 64 + lane];
            acc[e] = fmaf(xv.x, wv.x, acc[e]);
            acc[e] = fmaf(xv.y, wv.y, acc[e]);
            acc[e] = fmaf(xv.z, wv.z, acc[e]);
            acc[e] = fmaf(xv.w, wv.w, acc[e]);
        }
    }
#pragma unroll
    for (int e = 0; e < NE; ++e) {
        float v = acc[e];
#pragma unroll
        for (int off = 32; off > 0; off >>= 1) v += __shfl_xor(v, off, 64);
        acc[e] = v;
    }
    if (lane == 0) {
        float l[NE];
#pragma unroll
        for (int e = 0; e < NE; ++e) l[e] = acc[e] + br[e];
        int i0 = 0; float v0 = l[0];
#pragma unroll
        for (int e = 1; e < NE; ++e) if (l[e] > v0) { v0 = l[e]; i0 = e; }
        int i1 = -1; float v1 = -3.4e38f;
#pragma unroll
        for (int e = 0; e < NE; ++e) if (e != i0 && l[e] > v1) { v1 = l[e]; i1 = e; }
        float e1 = expf(v1 - v0);
        float g0 = 1.f / (1.f + e1);
        float g1 = e1 * g0;
        tokIdx[2 * t] = i0;  tokIdx[2 * t + 1] = i1;
        tokGate[2 * t] = g0; tokGate[2 * t + 1] = g1;
    }
}

__global__ __launch_bounds__(64) void count_kernel(
    const int* __restrict__ tokIdx, int* __restrict__ chunkCounts)
{
    int lane = threadIdx.x;
    int t = blockIdx.x * 64 + lane;
    int i0 = tokIdx[2 * t], i1 = tokIdx[2 * t + 1];
#pragma unroll
    for (int e = 0; e < NE; ++e) {
        unsigned long long m = __ballot(i0 == e || i1 == e);
        if (lane == 0) chunkCounts[e * NCHUNK + blockIdx.x] = __popcll(m);
    }
}

__global__ __launch_bounds__(256) void scan_kernel(
    const int* __restrict__ chunkCounts, int* __restrict__ chunkOffs,
    float* __restrict__ outTail)
{
    __shared__ int s[NCHUNK];
    __shared__ int totals[NE];
    int tid = threadIdx.x;
    for (int e = 0; e < NE; ++e) {
        int v = chunkCounts[e * NCHUNK + tid];
        s[tid] = v;
        __syncthreads();
        for (int off = 1; off < NCHUNK; off <<= 1) {
            int add = (tid >= off) ? s[tid - off] : 0;
            __syncthreads();
            s[tid] += add;
            __syncthreads();
        }
        chunkOffs[e * NCHUNK + tid] = s[tid] - v;
        if (tid == NCHUNK - 1) totals[e] = s[tid];
        __syncthreads();
    }
    if (tid == 0) {
        float load[NE]; float sum = 0.f;
        for (int e = 0; e < NE; ++e) {
            int c = totals[e]; if (c > CAP) c = CAP;
            load[e] = (float)c; sum += load[e];
        }
        float inv = 1.f / (sum + 1e-8f);
        float loss = 0.f;
        for (int e = 0; e < NE; ++e) {
            float d = load[e] * inv;
            loss -= d * logf(d + 1e-8f);
            outTail[1 + e] = d;
        }
        outTail[0] = loss;
    }
}

__global__ __launch_bounds__(64) void emit_kernel(
    const int* __restrict__ tokIdx, const float* __restrict__ tokGate,
    const int* __restrict__ chunkOffs, int* __restrict__ expTok,
    float* __restrict__ expGate, int* __restrict__ tokenSlot)
{
    int lane = threadIdx.x;
    int t = blockIdx.x * 64 + lane;
    int i0 = tokIdx[2 * t], i1 = tokIdx[2 * t + 1];
    float g0 = tokGate[2 * t], g1 = tokGate[2 * t + 1];
#pragma unroll
    for (int e = 0; e < NE; ++e) {
        bool r0 = (i0 == e), r1 = (i1 == e);
        unsigned long long m = __ballot(r0 || r1);
        if (r0 || r1) {
            int rank = chunkOffs[e * NCHUNK + blockIdx.x] +
                       __popcll(m & ((1ull << lane) - 1ull));
            int k = r0 ? 0 : 1;
            if (rank < CAP) {
                expTok[e * CAP + rank] = t;
                expGate[e * CAP + rank] = r0 ? g0 : g1;
                tokenSlot[2 * t + k] = e * CAP + rank;
            } else {
                tokenSlot[2 * t + k] = -1;
            }
        }
    }
}

// ---------------------------------------------------
// fp32 -> bf16 hi/lo plane conversion (vectorized, 4 elems/thread)
__global__ __launch_bounds__(256) void convert_kernel(
    const float* __restrict__ src, short* __restrict__ hi,
    short* __restrict__ lo, int n4)
{
    int i = blockIdx.x * 256 + threadIdx.x;
    if (i >= n4) return;
    float4 v = ((const float4*)src)[i];
    short4v h, l;
    h.x = f2bf(v.x); h.y = f2bf(v.y); h.z = f2bf(v.z); h.w = f2bf(v.w);
    l.x = f2bf(v.x - bf2f(h.x)); l.y = f2bf(v.y - bf2f(h.y));
    l.z = f2bf(v.z - bf2f(h.z)); l.w = f2bf(v.w - bf2f(h.w));
    ((short4v*)hi)[i] = h;
    ((short4v*)lo)[i] = l;
}

// gather x rows into per-slot A planes (bf16 hi/lo). One block per slot.
__global__ __launch_bounds__(256) void gather_kernel(
    const float* __restrict__ x, const int* __restrict__ expTok,
    short* __restrict__ Ahi, short* __restrict__ Alo)
{
    int slot = blockIdx.x;
    int tok = expTok[slot];
    int c = threadIdx.x * 4;
    float4 v = *(const float4*)(x + (size_t)tok * DIM + c);
    short4v h, l;
    h.x = f2bf(v.x); h.y = f2bf(v.y); h.z = f2bf(v.z); h.w = f2bf(v.w);
    l.x = f2bf(v.x - bf2f(h.x)); l.y = f2bf(v.y - bf2f(h.y));
    l.z = f2bf(v.z - bf2f(h.z)); l.w = f2bf(v.w - bf2f(h.w));
    *(short4v*)(Ahi + (size_t)slot * DIM + c) = h;
    *(short4v*)(Alo + (size_t)slot * DIM + c) = l;
}

// ---------------------------------------------------
// Split-bf16 MFMA GEMM v3: 128x128 tile, BK=64, 4 waves,
// 3-buffer LDS (96KB), 2-deep prefetch, counted vmcnt (T4: never 0 in
// steady state), raw s_barrier x2/iter, T2 both-sides swizzle,
// T1 XCD-chunked block swizzle, T5 setprio.
// Effective K' = 3*DIM via segment plane-mux:
//   seg0 Ahi*Bhi, seg1 Ahi*Blo, seg2 Alo*Bhi.
// C[c,o] = sum_d A[c,d] * W[o,d]
// MODE 0: epilogue relu(acc+b) -> Ohi/Olo bf16 planes (h)
// MODE 1: epilogue (acc+b)*gate -> EO fp32
//
// LDS per buffer: A [128][64] bf16 (128B rows) swizzled (16B slot s of row r
// at slot s^(r&7)), then B same. gload_lds writes linearly; the per-lane
// GLOBAL column is pre-swizzled (rule #21) so the linear write lands the
// swizzled layout; ds_read applies the same XOR.
//
// Liveness: stage(t+2) overwrites buf((t+2)%3) = buf((t-1)%3), freed by
// iter (t-1)'s second barrier (each wave's ds_reads were consumed by its
// MFMAs -- lgkmcnt -- before reaching that barrier).
// vmcnt ledger (8 loads/wave/stage): at iter-t wait, outstanding =
// t(8,oldest)+t+1(8)+t+2(8 if staged) -> wait 16 (t<46), 8 (t==46), 0 (t==47).

__device__ __forceinline__ void stage_tile(
    const short* __restrict__ aP, const short* __restrict__ bP,
    int rowBaseA, int rowBaseB, int k0,
    char* ldsA, char* ldsB, int wave, int lane)
{
    const int srow  = lane >> 3;                 // row within 8-row group
    const int xcol  = ((lane & 7) ^ srow) * 8;   // pre-swizzled col (shorts)
    const short* ga = aP + (size_t)(rowBaseA + wave * 32 + srow) * DIM + k0 + xcol;
    const short* gb = bP + (size_t)(rowBaseB + wave * 32 + srow) * DIM + k0 + xcol;
    char* la = ldsA + (wave * 32) * 128;
    char* lb = ldsB + (wave * 32) * 128;
#pragma unroll
    for (int g = 0; g < 4; ++g)
        gload_lds16(ga + (size_t)(g * 8) * DIM, la + g * 1024);
#pragma unroll
    for (int g = 0; g < 4; ++g)
        gload_lds16(gb + (size_t)(g * 8) * DIM, lb + g * 1024);
}

template <int MODE>
__global__ __launch_bounds__(256, 1) void mfma_gemm(
    const short* __restrict__ Ahi, const short* __restrict__ Alo,
    const short* __restrict__ Whi, const short* __restrict__ Wlo,
    const float* __restrict__ bias, const float* __restrict__ expGate,
    short* __restrict__ Ohi, short* __restrict__ Olo,
    float* __restrict__ EO)
{
    __shared__ __align__(16) char lds[98304];    // 3 buf x [A 16KB | B 16KB]

    // T1: bijective XCD-chunk swizzle (nwg=1280, 8 XCDs, 160/XCD = 1 expert/XCD)
    const int flat = blockIdx.x;
    const int swz  = (flat & 7) * 160 + (flat >> 3);
    const int e  = swz / 160;
    const int r  = swz % 160;
    const int tm = r >> 3;          // 0..19
    const int tn = r & 7;           // 0..7

    const int tid  = threadIdx.x;
    const int wave = tid >> 6;
    const int lane = tid & 63;
    const int wm = (wave >> 1) * 64;
    const int wn = (wave & 1) * 64;

    const int rowBaseA = e * CAP + tm * 128;
    const int rowBaseB = tn * 128;
    const short* Wh = Whi + (size_t)e * DIM * DIM;
    const short* Wl = Wlo + (size_t)e * DIM * DIM;

    const int frow = lane & 15;
    const int fq   = lane >> 4;

    floatx4 acc[4][4];
#pragma unroll
    for (int i = 0; i < 4; ++i)
#pragma unroll
        for (int j = 0; j < 4; ++j) acc[i][j] = (floatx4)0.f;

    // prologue: stage tiles 0,1 (both seg 0)
    stage_tile(Ahi, Wh, rowBaseA, rowBaseB, 0,  lds,         lds + 16384, wave, lane);
    stage_tile(Ahi, Wh, rowBaseA, rowBaseB, 64, lds + 32768, lds + 49152, wave, lane);

    // 48 K-tiles of 64 (3 segments x 16)
#pragma unroll 1
    for (int t = 0; t < 48; ++t) {
        char* bufA = lds + (t % 3) * 32768;
        char* bufB = bufA + 16384;
        const int t2 = t + 2;
        if (t2 < 48) {
            const int seg = t2 >> 4;
            const int k0  = (t2 & 15) << 6;
            const short* aP = (seg == 2) ? Alo : Ahi;
            const short* bP = (seg == 1) ? Wl : Wh;
            char* dstA = lds + (t2 % 3) * 32768;
            stage_tile(aP, bP, rowBaseA, rowBaseB, k0, dstA, dstA + 16384,
                       wave, lane);
        }
        if (t < 46)       asm volatile("s_waitcnt vmcnt(16)" ::: "memory");
        else if (t == 46) asm volatile("s_waitcnt vmcnt(8)"  ::: "memory");
        else              asm volatile("s_waitcnt vmcnt(0)"  ::: "memory");
        __builtin_amdgcn_sched_barrier(0);
        __builtin_amdgcn_s_barrier();       // #1: tile t visible to all waves
        __builtin_amdgcn_sched_barrier(0);
#pragma unroll
        for (int kc = 0; kc < 2; ++kc) {
            const int bo = ((kc * 4 + fq) ^ (frow & 7)) * 16;  // swizzled byte-in-row
            short8 af[4], bf[4];
#pragma unroll
            for (int i = 0; i < 4; ++i)
                af[i] = *(const short8*)(bufA + (wm + i * 16 + frow) * 128 + bo);
#pragma unroll
            for (int j = 0; j < 4; ++j)
                bf[j] = *(const short8*)(bufB + (wn + j * 16 + frow) * 128 + bo);
            __builtin_amdgcn_s_setprio(1);
#pragma unroll
            for (int i = 0; i < 4; ++i)
#pragma unroll
                for (int j = 0; j < 4; ++j)
                    acc[i][j] = __builtin_amdgcn_mfma_f32_16x16x32_bf16(
                        af[i], bf[j], acc[i][j], 0, 0, 0);
            __builtin_amdgcn_s_setprio(0);
        }
        __builtin_amdgcn_sched_barrier(0);
        __builtin_amdgcn_s_barrier();       // #2: frees buf(t%3) for stage(t+3)
    }

    // epilogue. C/D layout: col = lane&15, row = (lane>>4)*4 + reg
    const int colBase = tn * 128 + wn;
#pragma unroll
    for (int j = 0; j < 4; ++j) {
        const int gc = colBase + j * 16 + (lane & 15);
        const float bj = bias[(size_t)e * DIM + gc];
#pragma unroll
        for (int i = 0; i < 4; ++i) {
            const int lr0 = wm + i * 16 + (lane >> 4) * 4;
#pragma unroll
            for (int rr = 0; rr < 4; ++rr) {
                const int lr = tm * 128 + lr0 + rr;          // row within expert
                float v = acc[i][j][rr] + bj;
                if (MODE == 0) {
                    v = fmaxf(v, 0.f);
                    short hi = f2bf(v);
                    short lo = f2bf(v - bf2f(hi));
                    size_t idx = (size_t)(e * CAP + lr) * DIM + gc;
                    Ohi[idx] = hi;
                    Olo[idx] = lo;
                } else {
                    float g = expGate[e * CAP + lr];
                    EO[(size_t)(e * CAP + lr) * DIM + gc] = v * g;
                }
            }
        }
    }
}

// Deterministic combine: out[t] = sum of the token's (<=2) kept expert rows.
__global__ __launch_bounds__(256) void combine_kernel(
    const float* __restrict__ EO, const int* __restrict__ tokenSlot,
    float* __restrict__ out)
{
    int t = blockIdx.x;
    int col = threadIdx.x * 4;
    int p0 = tokenSlot[2 * t], p1 = tokenSlot[2 * t + 1];
    float4 s = make_float4(0.f, 0.f, 0.f, 0.f);
    if (p0 >= 0) {
        float4 v = *(const float4*)(EO + (size_t)p0 * DIM + col);
        s.x += v.x; s.y += v.y; s.z += v.z; s.w += v.w;
    }
    if (p1 >= 0) {
        float4 v = *(const float4*)(EO + (size_t)p1 * DIM + col);
        s.x += v.x; s.y += v.y; s.z += v.z; s.w += v.w;
    }
    *(float4*)(out + (size_t)t * DIM + col) = s;
}

// ---------------------------------------------------
// fp32 fallback GEMMs (used only if workspace is too small for MFMA path)
#define BM 128
#define BN 128
#define BKF 8

__global__ __launch_bounds__(256) void f32gemm1_kernel(
    const float* __restrict__ x, const float* __restrict__ W1,
    const float* __restrict__ b1, const int* __restrict__ expTok,
    float* __restrict__ h)
{
    int e = blockIdx.z;
    int tm = blockIdx.x, tn = blockIdx.y;
    const float* W = W1 + (size_t)e * DIM * DIM;
    __shared__ float As[BKF][BM];
    __shared__ float Bs[BKF][BN];
    int tid = threadIdx.x;
    int lrow = tid >> 1, lk4 = (tid & 1) * 4;
    int rm = tid >> 4, rn = tid & 15;
    int tok = expTok[e * CAP + tm * BM + lrow];
    const float* aPtr = x + (size_t)tok * DIM + lk4;
    const float* bPtr = W + (size_t)(tn * BN + lrow) * DIM + lk4;
    float acc[8][8];
#pragma unroll
    for (int i = 0; i < 8; ++i)
#pragma unroll
        for (int j = 0; j < 8; ++j) acc[i][j] = 0.f;
    for (int k0 = 0; k0 < DIM; k0 += BKF) {
        float4 av = *(const float4*)(aPtr + k0);
        float4 bv = *(const float4*)(bPtr + k0);
        __syncthreads();
        As[lk4 + 0][lrow] = av.x; As[lk4 + 1][lrow] = av.y;
        As[lk4 + 2][lrow] = av.z; As[lk4 + 3][lrow] = av.w;
        Bs[lk4 + 0][lrow] = bv.x; Bs[lk4 + 1][lrow] = bv.y;
        Bs[lk4 + 2][lrow] = bv.z; Bs[lk4 + 3][lrow] = bv.w;
        __syncthreads();
#pragma unroll
        for (int k = 0; k < BKF; ++k) {
            float4 a0 = *(const float4*)&As[k][rm * 4];
            float4 a1 = *(const float4*)&As[k][64 + rm * 4];
            float4 b0 = *(const float4*)&Bs[k][rn * 4];
            float4 b1r = *(const float4*)&Bs[k][64 + rn * 4];
            float ar[8] = {a0.x,a0.y,a0.z,a0.w,a1.x,a1.y,a1.z,a1.w};
            float bc[8] = {b0.x,b0.y,b0.z,b0.w,b1r.x,b1r.y,b1r.z,b1r.w};
#pragma unroll
            for (int i = 0; i < 8; ++i)
#pragma unroll
                for (int j = 0; j < 8; ++j)
                    acc[i][j] = fmaf(ar[i], bc[j], acc[i][j]);
        }
    }
    int o0 = tn * BN + rn * 4;
    float4 blo = *(const float4*)(b1 + e * DIM + o0);
    float4 bhi = *(const float4*)(b1 + e * DIM + o0 + 64);
#pragma unroll
    for (int i = 0; i < 8; ++i) {
        int c = tm * BM + ((i < 4) ? (rm * 4 + i) : (64 + rm * 4 + i - 4));
        float* hr = h + ((size_t)e * CAP + c) * DIM;
        float4 lo = make_float4(fmaxf(acc[i][0] + blo.x, 0.f),
                                fmaxf(acc[i][1] + blo.y, 0.f),
                                fmaxf(acc[i][2] + blo.z, 0.f),
                                fmaxf(acc[i][3] + blo.w, 0.f));
        float4 hi = make_float4(fmaxf(acc[i][4] + bhi.x, 0.f),
                                fmaxf(acc[i][5] + bhi.y, 0.f),
                                fmaxf(acc[i][6] + bhi.z, 0.f),
                                fmaxf(acc[i][7] + bhi.w, 0.f));
        *(float4*)(hr + o0) = lo;
        *(float4*)(hr + o0 + 64) = hi;
    }
}

__global__ __launch_bounds__(256) void f32gemm2_kernel(
    const float* __restrict__ h, const float* __restrict__ W2,
    const float* __restrict__ b2, const int* __restrict__ expTok,
    const float* __restrict__ expGate, float* __restrict__ out)
{
    int e = blockIdx.z;
    int tm = blockIdx.x, tn = blockIdx.y;
    const float* W = W2 + (size_t)e * DIM * DIM;
    __shared__ float As[BKF][BM];
    __shared__ float Bs[BKF][BN];
    int tid = threadIdx.x;
    int lrow = tid >> 1, lk4 = (tid & 1) * 4;
    int rm = tid >> 4, rn = tid & 15;
    const float* aPtr = h + ((size_t)e * CAP + tm * BM + lrow) * DIM + lk4;
    const float* bPtr = W + (size_t)(tn * BN + lrow) * DIM + lk4;
    float acc[8][8];
#pragma unroll
    for (int i = 0; i < 8; ++i)
#pragma unroll
        for (int j = 0; j < 8; ++j) acc[i][j] = 0.f;
    for (int k0 = 0; k0 < DIM; k0 += BKF) {
        float4 av = *(const float4*)(aPtr + k0);
        float4 bv = *(const float4*)(bPtr + k0);
        __syncthreads();
        As[lk4 + 0][lrow] = av.x; As[lk4 + 1][lrow] = av.y;
        As[lk4 + 2][lrow] = av.z; As[lk4 + 3][lrow] = av.w;
        Bs[lk4 + 0][lrow] = bv.x; Bs[lk4 + 1][lrow] = bv.y;
        Bs[lk4 + 2][lrow] = bv.z; Bs[lk4 + 3][lrow] = bv.w;
        __syncthreads();
#pragma unroll
        for (int k = 0; k < BKF; ++k) {
            float4 a0 = *(const float4*)&As[k][rm * 4];
            float4 a1 = *(const float4*)&As[k][64 + rm * 4];
            float4 b0 = *(const float4*)&Bs[k][rn * 4];
            float4 b1r = *(const float4*)&Bs[k][64 + rn * 4];
            float ar[8] = {a0.x,a0.y,a0.z,a0.w,a1.x,a1.y,a1.z,a1.w};
            float bc[8] = {b0.x,b0.y,b0.z,b0.w,b1r.x,b1r.y,b1r.z,b1r.w};
#pragma unroll
            for (int i = 0; i < 8; ++i)
#pragma unroll
                for (int j = 0; j < 8; ++j)
                    acc[i][j] = fmaf(ar[i], bc[j], acc[i][j]);
        }
    }
    int o0 = tn * BN + rn * 4;
    float4 blo = *(const float4*)(b2 + e * DIM + o0);
    float4 bhi = *(const float4*)(b2 + e * DIM + o0 + 64);
#pragma unroll
    for (int i = 0; i < 8; ++i) {
        int c = tm * BM + ((i < 4) ? (rm * 4 + i) : (64 + rm * 4 + i - 4));
        float g = expGate[e * CAP + c];
        if (g != 0.f) {
            int t = expTok[e * CAP + c];
            float* orow = out + (size_t)t * DIM;
            atomicAdd(orow + o0 + 0, (acc[i][0] + blo.x) * g);
            atomicAdd(orow + o0 + 1, (acc[i][1] + blo.y) * g);
            atomicAdd(orow + o0 + 2, (acc[i][2] + blo.z) * g);
            atomicAdd(orow + o0 + 3, (acc[i][3] + blo.w) * g);
            atomicAdd(orow + o0 + 64, (acc[i][4] + bhi.x) * g);
            atomicAdd(orow + o0 + 65, (acc[i][5] + bhi.y) * g);
            atomicAdd(orow + o0 + 66, (acc[i][6] + bhi.z) * g);
            atomicAdd(orow + o0 + 67, (acc[i][7] + bhi.w) * g);
        }
    }
}

// ---------------------------------------------------
extern "C" void kernel_launch(void* const* d_in, const int* in_sizes, int n_in,
                              void* d_out, int out_size, void* d_ws, size_t ws_size,
                              hipStream_t stream)
{
    const float* x  = (const float*)d_in[0];
    const float* Wr = (const float*)d_in[1];
    const float* br = (const float*)d_in[2];
    const float* W1 = (const float*)d_in[3];
    const float* b1 = (const float*)d_in[4];
    const float* W2 = (const float*)d_in[5];
    const float* b2 = (const float*)d_in[6];
    float* out = (float*)d_out;

    char* ws = (char*)d_ws;
    const size_t needMfma = 4 * APL_BYTES + 4 * WPL_BYTES + SMALL_BYTES;

    if (ws_size >= needMfma) {
        // ---- MFMA split-bf16 path ----
        size_t off = 0;
        short* Ahi = (short*)(ws + off); off += APL_BYTES;
        short* Alo = (short*)(ws + off); off += APL_BYTES;
        short* Hhi = (short*)(ws + off); off += APL_BYTES;
        short* Hlo = (short*)(ws + off); off += APL_BYTES;
        short* W1h = (short*)(ws + off); off += WPL_BYTES;
        short* W1l = (short*)(ws + off); off += WPL_BYTES;
        short* W2h = (short*)(ws + off); off += WPL_BYTES;
        short* W2l = (short*)(ws + off); off += WPL_BYTES;
        int*   expTok  = (int*)(ws + off);   off += TOK_BYTES;
        float* expGate = (float*)(ws + off); off += GATE_BYTES;
        int*   tokIdx  = (int*)(ws + off);   off += TIDX_BYTES;
        float* tokGate = (float*)(ws + off); off += TGT_BYTES;
        int*   tokenSlot = (int*)(ws + off); off += TSLOT_BYTES;
        int*   chunkCounts = (int*)(ws + off); off += CC_BYTES;
        int*   chunkOffs   = (int*)(ws + off); off += CO_BYTES;
        // EO aliases the A planes (A is dead after gemm1; stream-ordered)
        float* EO = (float*)Ahi;

        hipMemsetAsync(expTok, 0, TOK_BYTES + GATE_BYTES, stream);

        router_kernel<<<N_TOK / 4, 256, 0, stream>>>(x, Wr, br, tokIdx, tokGate);
        count_kernel<<<NCHUNK, 64, 0, stream>>>(tokIdx, chunkCounts);
        scan_kernel<<<1, 256, 0, stream>>>(chunkCounts, chunkOffs,
                                           out + (size_t)N_TOK * DIM);
        emit_kernel<<<NCHUNK, 64, 0, stream>>>(tokIdx, tokGate, chunkOffs,
                                               expTok, expGate, tokenSlot);

        const int wN4 = NE * DIM * DIM / 4;   // 2,097,152
        convert_kernel<<<wN4 / 256, 256, 0, stream>>>(W1, W1h, W1l, wN4);
        convert_kernel<<<wN4 / 256, 256, 0, stream>>>(W2, W2h, W2l, wN4);
        gather_kernel<<<NSLOT, 256, 0, stream>>>(x, expTok, Ahi, Alo);

        const int nblk = (NSLOT / 128) * (DIM / 128);   // 1280
        mfma_gemm<0><<<nblk, 256, 0, stream>>>(Ahi, Alo, W1h, W1l, b1, nullptr,
                                               Hhi, Hlo, nullptr);
        mfma_gemm<1><<<nblk, 256, 0, stream>>>(Hhi, Hlo, W2h, W2l, b2, expGate,
                                               nullptr, nullptr, EO);
        combine_kernel<<<N_TOK, 256, 0, stream>>>(EO, tokenSlot, out);
    } else {
        // ---- fp32 fallback (atomic combine) ----
        size_t off = 0;
        float* h = (float*)(ws + off); off += H_BYTES;
        int*   expTok  = (int*)(ws + off);   off += TOK_BYTES;
        float* expGate = (float*)(ws + off); off += GATE_BYTES;
        int*   tokIdx  = (int*)(ws + off);   off += TIDX_BYTES;
        float* tokGate = (float*)(ws + off); off += TGT_BYTES;
        int*   tokenSlot = (int*)(ws + off); off += TSLOT_BYTES;
        int*   chunkCounts = (int*)(ws + off); off += CC_BYTES;
        int*   chunkOffs   = (int*)(ws + off); off += CO_BYTES;

        hipMemsetAsync(expTok, 0, TOK_BYTES + GATE_BYTES, stream);
        hipMemsetAsync(out, 0, (size_t)N_TOK * DIM * sizeof(float), stream);

        router_kernel<<<N_TOK / 4, 256, 0, stream>>>(x, Wr, br, tokIdx, tokGate);
        count_kernel<<<NCHUNK, 64, 0, stream>>>(tokIdx, chunkCounts);
        scan_kernel<<<1, 256, 0, stream>>>(chunkCounts, chunkOffs,
                                           out + (size_t)N_TOK * DIM);
        emit_kernel<<<NCHUNK, 64, 0, stream>>>(tokIdx, tokGate, chunkOffs,
                                               expTok, expGate, tokenSlot);

        dim3 gg(CAP / BM, DIM / BN, NE);
        f32gemm1_kernel<<<gg, 256, 0, stream>>>(x, W1, b1, expTok, h);
        f32gemm2_kernel<<<gg, 256, 0, stream>>>(h, W2, b2, expTok, expGate, out);
    }
}

// Round 7
// 505.867 us; speedup vs baseline: 1.2252x; 1.2252x over previous
//
#include <hip/hip_runtime.h>
#include <hip/hip_bf16.h>
#include <cstdint>
#include <cstddef>

// ---------------- problem constants ----------------
#define N_TOK   16384
#define DIM     1024
#define NE      8
#define CAP     2560        // int(1.25 * 16384 / 8)
#define NCHUNK  256         // 16384 / 64
#define NSLOT   (NE * CAP)  // 20480

// ---------------- sizes -----------------
#define APL_BYTES  ((size_t)NSLOT * DIM * 2)      // one bf16 plane of A/H: 41,943,040
#define WPL_BYTES  ((size_t)NE * DIM * DIM * 2)   // one bf16 plane of W:   16,777,216
#define H_BYTES    ((size_t)NSLOT * DIM * 4)      // fp32 h (fallback path)
#define TOK_BYTES  ((size_t)NSLOT * 4)
#define GATE_BYTES ((size_t)NSLOT * 4)
#define TIDX_BYTES ((size_t)N_TOK * 2 * 4)
#define TGT_BYTES  ((size_t)N_TOK * 2 * 4)
#define TSLOT_BYTES ((size_t)N_TOK * 2 * 4)
#define CC_BYTES   ((size_t)NE * NCHUNK * 4)
#define CO_BYTES   ((size_t)NE * NCHUNK * 4)
#define SMALL_BYTES (TOK_BYTES + GATE_BYTES + TIDX_BYTES + TGT_BYTES + TSLOT_BYTES + CC_BYTES + CO_BYTES)

typedef __attribute__((ext_vector_type(8))) short short8;
typedef __attribute__((ext_vector_type(4))) short short4v;
typedef __attribute__((ext_vector_type(4))) float floatx4;

// bf16 helpers (RN-even), bit-pattern in short
__device__ __forceinline__ short f2bf(float f) {
    union { float f; unsigned u; } c; c.f = f;
    unsigned r = (c.u + 0x7fffu + ((c.u >> 16) & 1u)) >> 16;
    return (short)r;
}
__device__ __forceinline__ float bf2f(short s) {
    union { unsigned u; float f; } c; c.u = ((unsigned)(unsigned short)s) << 16;
    return c.f;
}

__device__ __forceinline__ void gload_lds16(const void* g, void* l) {
    typedef const __attribute__((address_space(1))) unsigned int* gp_t;
    typedef __attribute__((address_space(3))) unsigned int* lp_t;
    __builtin_amdgcn_global_load_lds((gp_t)g, (lp_t)l, 16, 0, 0);
}

// ---------------------------------------------------
// Router: one wave per token. logits = x @ Wr^T + br, top-2, softmax gates.
__global__ __launch_bounds__(256) void router_kernel(
    const float* __restrict__ x, const float* __restrict__ Wr,
    const float* __restrict__ br, int* __restrict__ tokIdx,
    float* __restrict__ tokGate)
{
    int wave = threadIdx.x >> 6;
    int lane = threadIdx.x & 63;
    int t = blockIdx.x * 4 + wave;

    float acc[NE];
#pragma unroll
    for (int e = 0; e < NE; ++e) acc[e] = 0.f;

    const float4* xr = (const float4*)(x + (size_t)t * DIM);
#pragma unroll
    for (int j = 0; j < 4; ++j) {
        float4 xv = xr[j * 64 + lane];
#pragma unroll
        for (int e = 0; e < NE; ++e) {
            float4 wv = ((const float4*)(Wr + e * DIM))[j * 64 + lane];
            acc[e] = fmaf(xv.x, wv.x, acc[e]);
            acc[e] = fmaf(xv.y, wv.y, acc[e]);
            acc[e] = fmaf(xv.z, wv.z, acc[e]);
            acc[e] = fmaf(xv.w, wv.w, acc[e]);
        }
    }
#pragma unroll
    for (int e = 0; e < NE; ++e) {
        float v = acc[e];
#pragma unroll
        for (int off = 32; off > 0; off >>= 1) v += __shfl_xor(v, off, 64);
        acc[e] = v;
    }
    if (lane == 0) {
        float l[NE];
#pragma unroll
        for (int e = 0; e < NE; ++e) l[e] = acc[e] + br[e];
        int i0 = 0; float v0 = l[0];
#pragma unroll
        for (int e = 1; e < NE; ++e) if (l[e] > v0) { v0 = l[e]; i0 = e; }
        int i1 = -1; float v1 = -3.4e38f;
#pragma unroll
        for (int e = 0; e < NE; ++e) if (e != i0 && l[e] > v1) { v1 = l[e]; i1 = e; }
        float e1 = expf(v1 - v0);
        float g0 = 1.f / (1.f + e1);
        float g1 = e1 * g0;
        tokIdx[2 * t] = i0;  tokIdx[2 * t + 1] = i1;
        tokGate[2 * t] = g0; tokGate[2 * t + 1] = g1;
    }
}

__global__ __launch_bounds__(64) void count_kernel(
    const int* __restrict__ tokIdx, int* __restrict__ chunkCounts)
{
    int lane = threadIdx.x;
    int t = blockIdx.x * 64 + lane;
    int i0 = tokIdx[2 * t], i1 = tokIdx[2 * t + 1];
#pragma unroll
    for (int e = 0; e < NE; ++e) {
        unsigned long long m = __ballot(i0 == e || i1 == e);
        if (lane == 0) chunkCounts[e * NCHUNK + blockIdx.x] = __popcll(m);
    }
}

// Wave-per-expert exclusive scan (shfl-based, no barriers in the scan).
__global__ __launch_bounds__(512) void scan_kernel(
    const int* __restrict__ chunkCounts, int* __restrict__ chunkOffs,
    float* __restrict__ outTail)
{
    __shared__ int totals[NE];
    int wave = threadIdx.x >> 6;       // expert
    int lane = threadIdx.x & 63;
    int running = 0;
#pragma unroll
    for (int g = 0; g < 4; ++g) {
        int idx = g * 64 + lane;
        int v = chunkCounts[wave * NCHUNK + idx];
        int s = v;
#pragma unroll
        for (int off = 1; off < 64; off <<= 1) {
            int u = __shfl_up(s, off, 64);
            if (lane >= off) s += u;
        }
        chunkOffs[wave * NCHUNK + idx] = running + s - v;
        running += __shfl(s, 63, 64);
    }
    if (lane == 0) totals[wave] = running;
    __syncthreads();
    if (threadIdx.x == 0) {
        float load[NE]; float sum = 0.f;
        for (int e = 0; e < NE; ++e) {
            int c = totals[e]; if (c > CAP) c = CAP;
            load[e] = (float)c; sum += load[e];
        }
        float inv = 1.f / (sum + 1e-8f);
        float loss = 0.f;
        for (int e = 0; e < NE; ++e) {
            float d = load[e] * inv;
            loss -= d * logf(d + 1e-8f);
            outTail[1 + e] = d;
        }
        outTail[0] = loss;
    }
}

__global__ __launch_bounds__(64) void emit_kernel(
    const int* __restrict__ tokIdx, const float* __restrict__ tokGate,
    const int* __restrict__ chunkOffs, int* __restrict__ expTok,
    float* __restrict__ expGate, int* __restrict__ tokenSlot)
{
    int lane = threadIdx.x;
    int t = blockIdx.x * 64 + lane;
    int i0 = tokIdx[2 * t], i1 = tokIdx[2 * t + 1];
    float g0 = tokGate[2 * t], g1 = tokGate[2 * t + 1];
#pragma unroll
    for (int e = 0; e < NE; ++e) {
        bool r0 = (i0 == e), r1 = (i1 == e);
        unsigned long long m = __ballot(r0 || r1);
        if (r0 || r1) {
            int rank = chunkOffs[e * NCHUNK + blockIdx.x] +
                       __popcll(m & ((1ull << lane) - 1ull));
            int k = r0 ? 0 : 1;
            if (rank < CAP) {
                expTok[e * CAP + rank] = t;
                expGate[e * CAP + rank] = r0 ? g0 : g1;
                tokenSlot[2 * t + k] = e * CAP + rank;
            } else {
                tokenSlot[2 * t + k] = -1;
            }
        }
    }
}

// ---------------------------------------------------
// fp32 -> bf16 hi/lo planes for W1 and W2 in one launch.
__global__ __launch_bounds__(256) void convert2_kernel(
    const float* __restrict__ W1, const float* __restrict__ W2,
    short* __restrict__ W1h, short* __restrict__ W1l,
    short* __restrict__ W2h, short* __restrict__ W2l, int n4each)
{
    int i = blockIdx.x * 256 + threadIdx.x;
    const float* src; short* hi; short* lo; int k;
    if (i < n4each) { src = W1; hi = W1h; lo = W1l; k = i; }
    else            { src = W2; hi = W2h; lo = W2l; k = i - n4each; }
    float4 v = ((const float4*)src)[k];
    short4v h, l;
    h.x = f2bf(v.x); h.y = f2bf(v.y); h.z = f2bf(v.z); h.w = f2bf(v.w);
    l.x = f2bf(v.x - bf2f(h.x)); l.y = f2bf(v.y - bf2f(h.y));
    l.z = f2bf(v.z - bf2f(h.z)); l.w = f2bf(v.w - bf2f(h.w));
    ((short4v*)hi)[k] = h;
    ((short4v*)lo)[k] = l;
}

// gather x rows into per-slot A planes (bf16 hi/lo). One block per slot.
__global__ __launch_bounds__(256) void gather_kernel(
    const float* __restrict__ x, const int* __restrict__ expTok,
    short* __restrict__ Ahi, short* __restrict__ Alo)
{
    int slot = blockIdx.x;
    int tok = expTok[slot];
    int c = threadIdx.x * 4;
    float4 v = *(const float4*)(x + (size_t)tok * DIM + c);
    short4v h, l;
    h.x = f2bf(v.x); h.y = f2bf(v.y); h.z = f2bf(v.z); h.w = f2bf(v.w);
    l.x = f2bf(v.x - bf2f(h.x)); l.y = f2bf(v.y - bf2f(h.y));
    l.z = f2bf(v.z - bf2f(h.z)); l.w = f2bf(v.w - bf2f(h.w));
    *(short4v*)(Ahi + (size_t)slot * DIM + c) = h;
    *(short4v*)(Alo + (size_t)slot * DIM + c) = l;
}

// ---------------------------------------------------
// Split-bf16 MFMA GEMM v4: 128x128 tile, BK=64, 4 waves, 2-buffer LDS
// (64KB -> 2 blocks/CU), 1-ahead prefetch with COUNTED vmcnt(8) (T4 --
// the wait targets loads issued a full iteration earlier; never drains
// the in-flight prefetch), raw s_barrier x2/iter, T2 both-sides swizzle,
// T1 XCD-chunked block swizzle, T5 setprio.
// Effective K' = 3*DIM via segment plane-mux:
//   seg0 Ahi*Bhi, seg1 Ahi*Blo, seg2 Alo*Bhi.
// C[c,o] = sum_d A[c,d] * W[o,d]
// MODE 0: epilogue relu(acc+b) -> Ohi/Olo bf16 planes (h)
// MODE 1: epilogue (acc+b)*gate -> EO fp32
//
// vmcnt ledger (8 loads/wave/stage): top of iter t issues stage(t+1);
// outstanding = stage(t)[8 oldest] + stage(t+1)[8] -> wait vmcnt(8)
// releases when stage(t) landed. t=47: nothing new issued -> vmcnt(0).
// Buffer safety: barrier #2 at end of iter t-1 guarantees every wave's
// ds_reads of buf[(t+1)&1] completed (MFMA issue forces lgkmcnt), so
// stage(t+1)'s overwrite at iter t top is safe.

__device__ __forceinline__ void stage_tile(
    const short* __restrict__ aP, const short* __restrict__ bP,
    int rowBaseA, int rowBaseB, int k0,
    char* ldsA, char* ldsB, int wave, int lane)
{
    const int srow  = lane >> 3;                 // row within 8-row group
    const int xcol  = ((lane & 7) ^ srow) * 8;   // pre-swizzled col (shorts)
    const short* ga = aP + (size_t)(rowBaseA + wave * 32 + srow) * DIM + k0 + xcol;
    const short* gb = bP + (size_t)(rowBaseB + wave * 32 + srow) * DIM + k0 + xcol;
    char* la = ldsA + (wave * 32) * 128;
    char* lb = ldsB + (wave * 32) * 128;
#pragma unroll
    for (int g = 0; g < 4; ++g)
        gload_lds16(ga + (size_t)(g * 8) * DIM, la + g * 1024);
#pragma unroll
    for (int g = 0; g < 4; ++g)
        gload_lds16(gb + (size_t)(g * 8) * DIM, lb + g * 1024);
}

template <int MODE>
__global__ __launch_bounds__(256) void mfma_gemm(
    const short* __restrict__ Ahi, const short* __restrict__ Alo,
    const short* __restrict__ Whi, const short* __restrict__ Wlo,
    const float* __restrict__ bias, const float* __restrict__ expGate,
    short* __restrict__ Ohi, short* __restrict__ Olo,
    float* __restrict__ EO)
{
    __shared__ __align__(16) char lds[65536];    // 2 buf x [A 16KB | B 16KB]

    // T1: bijective XCD-chunk swizzle (nwg=1280, 8 XCDs, 160/XCD = 1 expert/XCD)
    const int flat = blockIdx.x;
    const int swz  = (flat & 7) * 160 + (flat >> 3);
    const int e  = swz / 160;
    const int r  = swz % 160;
    const int tm = r >> 3;          // 0..19
    const int tn = r & 7;           // 0..7

    const int tid  = threadIdx.x;
    const int wave = tid >> 6;
    const int lane = tid & 63;
    const int wm = (wave >> 1) * 64;
    const int wn = (wave & 1) * 64;

    const int rowBaseA = e * CAP + tm * 128;
    const int rowBaseB = tn * 128;
    const short* Wh = Whi + (size_t)e * DIM * DIM;
    const short* Wl = Wlo + (size_t)e * DIM * DIM;

    const int frow = lane & 15;
    const int fq   = lane >> 4;

    floatx4 acc[4][4];
#pragma unroll
    for (int i = 0; i < 4; ++i)
#pragma unroll
        for (int j = 0; j < 4; ++j) acc[i][j] = (floatx4)0.f;

    // prologue: stage tile 0 into buf 0
    stage_tile(Ahi, Wh, rowBaseA, rowBaseB, 0, lds, lds + 16384, wave, lane);

    // 48 K-tiles of 64 (3 segments x 16)
#pragma unroll 1
    for (int t = 0; t < 48; ++t) {
        char* bufA = lds + (t & 1) * 32768;
        char* bufB = bufA + 16384;
        const int t1 = t + 1;
        if (t1 < 48) {
            const int seg = t1 >> 4;
            const int k0  = (t1 & 15) << 6;
            const short* aP = (seg == 2) ? Alo : Ahi;
            const short* bP = (seg == 1) ? Wl : Wh;
            char* dstA = lds + (t1 & 1) * 32768;
            stage_tile(aP, bP, rowBaseA, rowBaseB, k0, dstA, dstA + 16384,
                       wave, lane);
            asm volatile("s_waitcnt vmcnt(8)" ::: "memory");   // stage(t) done
        } else {
            asm volatile("s_waitcnt vmcnt(0)" ::: "memory");
        }
        __builtin_amdgcn_sched_barrier(0);
        __builtin_amdgcn_s_barrier();       // #1: tile t visible to all waves
        __builtin_amdgcn_sched_barrier(0);
#pragma unroll
        for (int kc = 0; kc < 2; ++kc) {
            const int bo = ((kc * 4 + fq) ^ (frow & 7)) * 16;  // swizzled byte-in-row
            short8 af[4], bf[4];
#pragma unroll
            for (int i = 0; i < 4; ++i)
                af[i] = *(const short8*)(bufA + (wm + i * 16 + frow) * 128 + bo);
#pragma unroll
            for (int j = 0; j < 4; ++j)
                bf[j] = *(const short8*)(bufB + (wn + j * 16 + frow) * 128 + bo);
            __builtin_amdgcn_s_setprio(1);
#pragma unroll
            for (int i = 0; i < 4; ++i)
#pragma unroll
                for (int j = 0; j < 4; ++j)
                    acc[i][j] = __builtin_amdgcn_mfma_f32_16x16x32_bf16(
                        af[i], bf[j], acc[i][j], 0, 0, 0);
            __builtin_amdgcn_s_setprio(0);
        }
        __builtin_amdgcn_sched_barrier(0);
        __builtin_amdgcn_s_barrier();       // #2: frees buf(t&1) for stage(t+2)
    }

    // epilogue. C/D layout: col = lane&15, row = (lane>>4)*4 + reg
    const int colBase = tn * 128 + wn;
#pragma unroll
    for (int j = 0; j < 4; ++j) {
        const int gc = colBase + j * 16 + (lane & 15);
        const float bj = bias[(size_t)e * DIM + gc];
#pragma unroll
        for (int i = 0; i < 4; ++i) {
            const int lr0 = wm + i * 16 + (lane >> 4) * 4;
#pragma unroll
            for (int rr = 0; rr < 4; ++rr) {
                const int lr = tm * 128 + lr0 + rr;          // row within expert
                float v = acc[i][j][rr] + bj;
                if (MODE == 0) {
                    v = fmaxf(v, 0.f);
                    short hi = f2bf(v);
                    short lo = f2bf(v - bf2f(hi));
                    size_t idx = (size_t)(e * CAP + lr) * DIM + gc;
                    Ohi[idx] = hi;
                    Olo[idx] = lo;
                } else {
                    float g = expGate[e * CAP + lr];
                    EO[(size_t)(e * CAP + lr) * DIM + gc] = v * g;
                }
            }
        }
    }
}

// Deterministic combine: out[t] = sum of the token's (<=2) kept expert rows.
__global__ __launch_bounds__(256) void combine_kernel(
    const float* __restrict__ EO, const int* __restrict__ tokenSlot,
    float* __restrict__ out)
{
    int t = blockIdx.x;
    int col = threadIdx.x * 4;
    int p0 = tokenSlot[2 * t], p1 = tokenSlot[2 * t + 1];
    float4 s = make_float4(0.f, 0.f, 0.f, 0.f);
    if (p0 >= 0) {
        float4 v = *(const float4*)(EO + (size_t)p0 * DIM + col);
        s.x += v.x; s.y += v.y; s.z += v.z; s.w += v.w;
    }
    if (p1 >= 0) {
        float4 v = *(const float4*)(EO + (size_t)p1 * DIM + col);
        s.x += v.x; s.y += v.y; s.z += v.z; s.w += v.w;
    }
    *(float4*)(out + (size_t)t * DIM + col) = s;
}

// ---------------------------------------------------
// fp32 fallback GEMMs (used only if workspace is too small for MFMA path)
#define BM 128
#define BN 128
#define BKF 8

__global__ __launch_bounds__(256) void f32gemm1_kernel(
    const float* __restrict__ x, const float* __restrict__ W1,
    const float* __restrict__ b1, const int* __restrict__ expTok,
    float* __restrict__ h)
{
    int e = blockIdx.z;
    int tm = blockIdx.x, tn = blockIdx.y;
    const float* W = W1 + (size_t)e * DIM * DIM;
    __shared__ float As[BKF][BM];
    __shared__ float Bs[BKF][BN];
    int tid = threadIdx.x;
    int lrow = tid >> 1, lk4 = (tid & 1) * 4;
    int rm = tid >> 4, rn = tid & 15;
    int tok = expTok[e * CAP + tm * BM + lrow];
    const float* aPtr = x + (size_t)tok * DIM + lk4;
    const float* bPtr = W + (size_t)(tn * BN + lrow) * DIM + lk4;
    float acc[8][8];
#pragma unroll
    for (int i = 0; i < 8; ++i)
#pragma unroll
        for (int j = 0; j < 8; ++j) acc[i][j] = 0.f;
    for (int k0 = 0; k0 < DIM; k0 += BKF) {
        float4 av = *(const float4*)(aPtr + k0);
        float4 bv = *(const float4*)(bPtr + k0);
        __syncthreads();
        As[lk4 + 0][lrow] = av.x; As[lk4 + 1][lrow] = av.y;
        As[lk4 + 2][lrow] = av.z; As[lk4 + 3][lrow] = av.w;
        Bs[lk4 + 0][lrow] = bv.x; Bs[lk4 + 1][lrow] = bv.y;
        Bs[lk4 + 2][lrow] = bv.z; Bs[lk4 + 3][lrow] = bv.w;
        __syncthreads();
#pragma unroll
        for (int k = 0; k < BKF; ++k) {
            float4 a0 = *(const float4*)&As[k][rm * 4];
            float4 a1 = *(const float4*)&As[k][64 + rm * 4];
            float4 b0 = *(const float4*)&Bs[k][rn * 4];
            float4 b1r = *(const float4*)&Bs[k][64 + rn * 4];
            float ar[8] = {a0.x,a0.y,a0.z,a0.w,a1.x,a1.y,a1.z,a1.w};
            float bc[8] = {b0.x,b0.y,b0.z,b0.w,b1r.x,b1r.y,b1r.z,b1r.w};
#pragma unroll
            for (int i = 0; i < 8; ++i)
#pragma unroll
                for (int j = 0; j < 8; ++j)
                    acc[i][j] = fmaf(ar[i], bc[j], acc[i][j]);
        }
    }
    int o0 = tn * BN + rn * 4;
    float4 blo = *(const float4*)(b1 + e * DIM + o0);
    float4 bhi = *(const float4*)(b1 + e * DIM + o0 + 64);
#pragma unroll
    for (int i = 0; i < 8; ++i) {
        int c = tm * BM + ((i < 4) ? (rm * 4 + i) : (64 + rm * 4 + i - 4));
        float* hr = h + ((size_t)e * CAP + c) * DIM;
        float4 lo = make_float4(fmaxf(acc[i][0] + blo.x, 0.f),
                                fmaxf(acc[i][1] + blo.y, 0.f),
                                fmaxf(acc[i][2] + blo.z, 0.f),
                                fmaxf(acc[i][3] + blo.w, 0.f));
        float4 hi = make_float4(fmaxf(acc[i][4] + bhi.x, 0.f),
                                fmaxf(acc[i][5] + bhi.y, 0.f),
                                fmaxf(acc[i][6] + bhi.z, 0.f),
                                fmaxf(acc[i][7] + bhi.w, 0.f));
        *(float4*)(hr + o0) = lo;
        *(float4*)(hr + o0 + 64) = hi;
    }
}

__global__ __launch_bounds__(256) void f32gemm2_kernel(
    const float* __restrict__ h, const float* __restrict__ W2,
    const float* __restrict__ b2, const int* __restrict__ expTok,
    const float* __restrict__ expGate, float* __restrict__ out)
{
    int e = blockIdx.z;
    int tm = blockIdx.x, tn = blockIdx.y;
    const float* W = W2 + (size_t)e * DIM * DIM;
    __shared__ float As[BKF][BM];
    __shared__ float Bs[BKF][BN];
    int tid = threadIdx.x;
    int lrow = tid >> 1, lk4 = (tid & 1) * 4;
    int rm = tid >> 4, rn = tid & 15;
    const float* aPtr = h + ((size_t)e * CAP + tm * BM + lrow) * DIM + lk4;
    const float* bPtr = W + (size_t)(tn * BN + lrow) * DIM + lk4;
    float acc[8][8];
#pragma unroll
    for (int i = 0; i < 8; ++i)
#pragma unroll
        for (int j = 0; j < 8; ++j) acc[i][j] = 0.f;
    for (int k0 = 0; k0 < DIM; k0 += BKF) {
        float4 av = *(const float4*)(aPtr + k0);
        float4 bv = *(const float4*)(bPtr + k0);
        __syncthreads();
        As[lk4 + 0][lrow] = av.x; As[lk4 + 1][lrow] = av.y;
        As[lk4 + 2][lrow] = av.z; As[lk4 + 3][lrow] = av.w;
        Bs[lk4 + 0][lrow] = bv.x; Bs[lk4 + 1][lrow] = bv.y;
        Bs[lk4 + 2][lrow] = bv.z; Bs[lk4 + 3][lrow] = bv.w;
        __syncthreads();
#pragma unroll
        for (int k = 0; k < BKF; ++k) {
            float4 a0 = *(const float4*)&As[k][rm * 4];
            float4 a1 = *(const float4*)&As[k][64 + rm * 4];
            float4 b0 = *(const float4*)&Bs[k][rn * 4];
            float4 b1r = *(const float4*)&Bs[k][64 + rn * 4];
            float ar[8] = {a0.x,a0.y,a0.z,a0.w,a1.x,a1.y,a1.z,a1.w};
            float bc[8] = {b0.x,b0.y,b0.z,b0.w,b1r.x,b1r.y,b1r.z,b1r.w};
#pragma unroll
            for (int i = 0; i < 8; ++i)
#pragma unroll
                for (int j = 0; j < 8; ++j)
                    acc[i][j] = fmaf(ar[i], bc[j], acc[i][j]);
        }
    }
    int o0 = tn * BN + rn * 4;
    float4 blo = *(const float4*)(b2 + e * DIM + o0);
    float4 bhi = *(const float4*)(b2 + e * DIM + o0 + 64);
#pragma unroll
    for (int i = 0; i < 8; ++i) {
        int c = tm * BM + ((i < 4) ? (rm * 4 + i) : (64 + rm * 4 + i - 4));
        float g = expGate[e * CAP + c];
        if (g != 0.f) {
            int t = expTok[e * CAP + c];
            float* orow = out + (size_t)t * DIM;
            atomicAdd(orow + o0 + 0, (acc[i][0] + blo.x) * g);
            atomicAdd(orow + o0 + 1, (acc[i][1] + blo.y) * g);
            atomicAdd(orow + o0 + 2, (acc[i][2] + blo.z) * g);
            atomicAdd(orow + o0 + 3, (acc[i][3] + blo.w) * g);
            atomicAdd(orow + o0 + 64, (acc[i][4] + bhi.x) * g);
            atomicAdd(orow + o0 + 65, (acc[i][5] + bhi.y) * g);
            atomicAdd(orow + o0 + 66, (acc[i][6] + bhi.z) * g);
            atomicAdd(orow + o0 + 67, (acc[i][7] + bhi.w) * g);
        }
    }
}

// ---------------------------------------------------
extern "C" void kernel_launch(void* const* d_in, const int* in_sizes, int n_in,
                              void* d_out, int out_size, void* d_ws, size_t ws_size,
                              hipStream_t stream)
{
    const float* x  = (const float*)d_in[0];
    const float* Wr = (const float*)d_in[1];
    const float* br = (const float*)d_in[2];
    const float* W1 = (const float*)d_in[3];
    const float* b1 = (const float*)d_in[4];
    const float* W2 = (const float*)d_in[5];
    const float* b2 = (const float*)d_in[6];
    float* out = (float*)d_out;

    char* ws = (char*)d_ws;
    const size_t needMfma = 4 * APL_BYTES + 4 * WPL_BYTES + SMALL_BYTES;

    if (ws_size >= needMfma) {
        // ---- MFMA split-bf16 path ----
        size_t off = 0;
        short* Ahi = (short*)(ws + off); off += APL_BYTES;
        short* Alo = (short*)(ws + off); off += APL_BYTES;
        short* Hhi = (short*)(ws + off); off += APL_BYTES;
        short* Hlo = (short*)(ws + off); off += APL_BYTES;
        short* W1h = (short*)(ws + off); off += WPL_BYTES;
        short* W1l = (short*)(ws + off); off += WPL_BYTES;
        short* W2h = (short*)(ws + off); off += WPL_BYTES;
        short* W2l = (short*)(ws + off); off += WPL_BYTES;
        int*   expTok  = (int*)(ws + off);   off += TOK_BYTES;
        float* expGate = (float*)(ws + off); off += GATE_BYTES;
        int*   tokIdx  = (int*)(ws + off);   off += TIDX_BYTES;
        float* tokGate = (float*)(ws + off); off += TGT_BYTES;
        int*   tokenSlot = (int*)(ws + off); off += TSLOT_BYTES;
        int*   chunkCounts = (int*)(ws + off); off += CC_BYTES;
        int*   chunkOffs   = (int*)(ws + off); off += CO_BYTES;
        // EO aliases the A planes (A is dead after gemm1; stream-ordered)
        float* EO = (float*)Ahi;

        hipMemsetAsync(expTok, 0, TOK_BYTES + GATE_BYTES, stream);

        router_kernel<<<N_TOK / 4, 256, 0, stream>>>(x, Wr, br, tokIdx, tokGate);
        count_kernel<<<NCHUNK, 64, 0, stream>>>(tokIdx, chunkCounts);
        scan_kernel<<<1, 512, 0, stream>>>(chunkCounts, chunkOffs,
                                           out + (size_t)N_TOK * DIM);
        emit_kernel<<<NCHUNK, 64, 0, stream>>>(tokIdx, tokGate, chunkOffs,
                                               expTok, expGate, tokenSlot);

        const int wN4 = NE * DIM * DIM / 4;   // 2,097,152
        convert2_kernel<<<2 * wN4 / 256, 256, 0, stream>>>(W1, W2, W1h, W1l,
                                                           W2h, W2l, wN4);
        gather_kernel<<<NSLOT, 256, 0, stream>>>(x, expTok, Ahi, Alo);

        const int nblk = (NSLOT / 128) * (DIM / 128);   // 1280
        mfma_gemm<0><<<nblk, 256, 0, stream>>>(Ahi, Alo, W1h, W1l, b1, nullptr,
                                               Hhi, Hlo, nullptr);
        mfma_gemm<1><<<nblk, 256, 0, stream>>>(Hhi, Hlo, W2h, W2l, b2, expGate,
                                               nullptr, nullptr, EO);
        combine_kernel<<<N_TOK, 256, 0, stream>>>(EO, tokenSlot, out);
    } else {
        // ---- fp32 fallback (atomic combine) ----
        size_t off = 0;
        float* h = (float*)(ws + off); off += H_BYTES;
        int*   expTok  = (int*)(ws + off);   off += TOK_BYTES;
        float* expGate = (float*)(ws + off); off += GATE_BYTES;
        int*   tokIdx  = (int*)(ws + off);   off += TIDX_BYTES;
        float* tokGate = (float*)(ws + off); off += TGT_BYTES;
        int*   tokenSlot = (int*)(ws + off); off += TSLOT_BYTES;
        int*   chunkCounts = (int*)(ws + off); off += CC_BYTES;
        int*   chunkOffs   = (int*)(ws + off); off += CO_BYTES;

        hipMemsetAsync(expTok, 0, TOK_BYTES + GATE_BYTES, stream);
        hipMemsetAsync(out, 0, (size_t)N_TOK * DIM * sizeof(float), stream);

        router_kernel<<<N_TOK / 4, 256, 0, stream>>>(x, Wr, br, tokIdx, tokGate);
        count_kernel<<<NCHUNK, 64, 0, stream>>>(tokIdx, chunkCounts);
        scan_kernel<<<1, 512, 0, stream>>>(chunkCounts, chunkOffs,
                                           out + (size_t)N_TOK * DIM);
        emit_kernel<<<NCHUNK, 64, 0, stream>>>(tokIdx, tokGate, chunkOffs,
                                               expTok, expGate, tokenSlot);

        dim3 gg(CAP / BM, DIM / BN, NE);
        f32gemm1_kernel<<<gg, 256, 0, stream>>>(x, W1, b1, expTok, h);
        f32gemm2_kernel<<<gg, 256, 0, stream>>>(h, W2, b2, expTok, expGate, out);
    }
}